// Round 5
// baseline (6175.451 us; speedup 1.0000x reference)
//
#include <hip/hip_runtime.h>

typedef unsigned short u16;
typedef unsigned int u32;
typedef __attribute__((ext_vector_type(8))) short short8v;
typedef __attribute__((ext_vector_type(4))) float f32x4;
typedef __attribute__((ext_vector_type(4))) unsigned int u32x4;

#define NB 64
#define NT 256
#define NM 512
#define NH 256

#define K2 2.8853900817779268f   // 2*log2(e)
#define LOG2E 1.4426950408889634f

__device__ __forceinline__ float bf2f(u16 u) {
  union { unsigned i; float f; } c; c.i = ((unsigned)u) << 16; return c.f;
}
__device__ __forceinline__ u16 f2bf(float f) {
  union { float fv; unsigned i; } c; c.fv = f;
  unsigned i = c.i;
  return (u16)((i + 0x7fffu + ((i >> 16) & 1u)) >> 16);
}
__device__ __forceinline__ float bits2f(u32 u) {
  union { unsigned i; float f; } c; c.i = u; return c.f;
}
__device__ __forceinline__ float tanh_fast(float x) {
  return 1.0f - 2.0f * __builtin_amdgcn_rcpf(1.0f + __builtin_amdgcn_exp2f(K2 * x));
}
__device__ __forceinline__ float sigmoid_fast(float x) {
  return __builtin_amdgcn_rcpf(1.0f + __builtin_amdgcn_exp2f(-LOG2E * x));
}

// ---- uncached (sc0 sc1: bypass L1/L2, coherence point = IF) helpers ----
__device__ __forceinline__ float unc_ld1(const float* p) {
  float r;
  asm volatile("global_load_dword %0, %1, off sc0 sc1\n\ts_waitcnt vmcnt(0)"
               : "=&v"(r) : "v"(p) : "memory");
  return r;
}
__device__ __forceinline__ void unc_ld1x4(const float* p0, const float* p1,
                                          const float* p2, const float* p3,
                                          float& a0, float& a1, float& a2, float& a3) {
  asm volatile(
      "global_load_dword %0, %4, off sc0 sc1\n\t"
      "global_load_dword %1, %5, off sc0 sc1\n\t"
      "global_load_dword %2, %6, off sc0 sc1\n\t"
      "global_load_dword %3, %7, off sc0 sc1\n\t"
      "s_waitcnt vmcnt(0)"
      : "=&v"(a0), "=&v"(a1), "=&v"(a2), "=&v"(a3)
      : "v"(p0), "v"(p1), "v"(p2), "v"(p3)
      : "memory");
}
// 4 consecutive dwordx4 from one base, ONE waitcnt (one round-trip)
// NOTE gfx950 asm syntax: offset:N must come BEFORE sc0 sc1
__device__ __forceinline__ void unc_ld16f(const float* p, f32x4& a, f32x4& b,
                                          f32x4& c, f32x4& d) {
  asm volatile(
      "global_load_dwordx4 %0, %4, off sc0 sc1\n\t"
      "global_load_dwordx4 %1, %4, off offset:16 sc0 sc1\n\t"
      "global_load_dwordx4 %2, %4, off offset:32 sc0 sc1\n\t"
      "global_load_dwordx4 %3, %4, off offset:48 sc0 sc1\n\t"
      "s_waitcnt vmcnt(0)"
      : "=&v"(a), "=&v"(b), "=&v"(c), "=&v"(d)
      : "v"(p) : "memory");
}
__device__ __forceinline__ void unc_st1(float* p, float v) {
  asm volatile("global_store_dword %0, %1, off sc0 sc1" :: "v"(p), "v"(v) : "memory");
}
__device__ __forceinline__ void unc_st1u(u32* p, u32 v) {
  asm volatile("global_store_dword %0, %1, off sc0 sc1" :: "v"(p), "v"(v) : "memory");
}
__device__ __forceinline__ void unc_st4(float* p, f32x4 v) {
  asm volatile("global_store_dwordx4 %0, %1, off sc0 sc1" :: "v"(p), "v"(v) : "memory");
}
__device__ __forceinline__ void drain_vmem() {
  asm volatile("s_waitcnt vmcnt(0)" ::: "memory");
}
__device__ __forceinline__ void pollflags(const u32* p, u32 tg) {
  for (;;) {
    u32x4 f;
    asm volatile("global_load_dwordx4 %0, %1, off sc0 sc1\n\ts_waitcnt vmcnt(0)"
                 : "=&v"(f) : "v"(p) : "memory");
    if (f[0] >= tg && f[1] >= tg && f[2] >= tg && f[3] >= tg) break;
    __builtin_amdgcn_s_sleep(1);
  }
}

__global__ void convert_f32_bf16(const float* __restrict__ in, u16* __restrict__ out, int n) {
  int i = blockIdx.x * blockDim.x + threadIdx.x;
  if (i < n) out[i] = f2bf(in[i]);
}

// y1' = K2 * enc @ Ud^T  (bf16 out, prescaled for exp2-based tanh)
__global__ __launch_bounds__(256) void gemm_y1(const u16* __restrict__ A,
                                               const u16* __restrict__ Bm,
                                               u16* __restrict__ C) {
  const int w = threadIdx.x >> 6;
  const int l = threadIdx.x & 63;
  const int kg = l >> 4;
  const int r16 = l & 15;
  const int rowbase = blockIdx.x * 64 + w * 16;
  const int colbase = blockIdx.y * 64;
  const u16* ap = A + (size_t)(rowbase + r16) * 512 + kg * 8;
  f32x4 acc0 = {0,0,0,0}, acc1 = {0,0,0,0}, acc2 = {0,0,0,0}, acc3 = {0,0,0,0};
  for (int k = 0; k < 512; k += 32) {
    short8v af = *(const short8v*)(ap + k);
    const u16* bp = Bm + (size_t)(colbase + r16) * 512 + kg * 8 + k;
    short8v b0 = *(const short8v*)(bp);
    short8v b1 = *(const short8v*)(bp + 16 * 512);
    short8v b2 = *(const short8v*)(bp + 32 * 512);
    short8v b3 = *(const short8v*)(bp + 48 * 512);
    acc0 = __builtin_amdgcn_mfma_f32_16x16x32_bf16(af, b0, acc0, 0, 0, 0);
    acc1 = __builtin_amdgcn_mfma_f32_16x16x32_bf16(af, b1, acc1, 0, 0, 0);
    acc2 = __builtin_amdgcn_mfma_f32_16x16x32_bf16(af, b2, acc2, 0, 0, 0);
    acc3 = __builtin_amdgcn_mfma_f32_16x16x32_bf16(af, b3, acc3, 0, 0, 0);
  }
  #pragma unroll
  for (int j = 0; j < 4; ++j) {
    int r = rowbase + (l >> 4) * 4 + j;
    C[(size_t)r * 512 + colbase +  0 + r16] = f2bf(K2 * acc0[j]);
    C[(size_t)r * 512 + colbase + 16 + r16] = f2bf(K2 * acc1[j]);
    C[(size_t)r * 512 + colbase + 32 + r16] = f2bf(K2 * acc2[j]);
    C[(size_t)r * 512 + colbase + 48 + r16] = f2bf(K2 * acc3[j]);
  }
}

// w_enc[b,te] = sum_m enc[b,te,m] * wtw[m]
__global__ __launch_bounds__(256) void wenc_kernel(const u16* __restrict__ encbf,
                                                   const float* __restrict__ wtw,
                                                   float* __restrict__ gwenc) {
  int b = blockIdx.x, te = threadIdx.x;
  const u16* ep = encbf + ((size_t)(b * NT + te)) * NM;
  float a = 0.0f;
  for (int c8 = 0; c8 < 64; ++c8) {
    short8v v = *(const short8v*)(ep + c8 * 8);
    #pragma unroll
    for (int jj = 0; jj < 8; ++jj) a = fmaf(bf2f((u16)v[jj]), wtw[c8 * 8 + jj], a);
  }
  gwenc[b * NT + te] = a;
}

__global__ __launch_bounds__(1024, 4) void attn_scan(
    const u16* __restrict__ y1bf,    // [B,T,M] prescaled by K2
    const u16* __restrict__ encbf,   // [B,T,M]
    const u16* __restrict__ whhbf,   // [1024,256]
    const u16* __restrict__ wdbf,    // [M,512]
    const float* __restrict__ Wd_b,  // [512]
    const float* __restrict__ vd,    // [512]
    const float* __restrict__ wtw,   // [513]
    const float* __restrict__ wtb,   // [1]
    const float* __restrict__ Wih,   // [1024]
    const float* __restrict__ bih,   // [1024]
    const float* __restrict__ bhh,   // [1024]
    const float* __restrict__ yin,   // [B,T]
    const float* __restrict__ gwenc, // [B,256]
    float* __restrict__ gx,          // [B][4][576]: 512 x1-partial + 64 dnew
    float* __restrict__ st,          // [B][4][4]: m_q, s_q, n_q, pad
    u32* __restrict__ flags,         // [B][32]: [0..3]=flagS, [8..11]=flagP
    float* __restrict__ out)         // [B,512]
{
  extern __shared__ char ldsraw[];
  u32* wdsl = (u32*)ldsraw;          // [512 m][64 dw] granule-swizzled bf16 pairs, 128 KiB

  __shared__ float x1_l[NM];
  __shared__ float d_l[NH];
  __shared__ float ds_f[128];        // dn(64) ; sn(64) of own k-slice
  __shared__ float l_sl[64];
  __shared__ float e_sl[64];
  __shared__ float whh_d_l[256];
  __shared__ float wih_l[256];
  __shared__ float bb_l[256];
  __shared__ float wdb_l[NM];
  __shared__ float wenc_sl[64];

  const int tid = threadIdx.x;
  const int bid = blockIdx.x;
  const int xcd = bid & 7, ii = bid >> 3;
  const int b = (xcd << 3) | (ii >> 2);   // 4 WGs of a batch on one XCD (locality only)
  const int q = ii & 3;
  const int w = tid >> 6, l = tid & 63;

  // ---- one-time init ----
  if (tid < 512) wdb_l[tid] = Wd_b[tid];
  if (tid < 256) {
    int g = tid >> 6, h = tid & 63;
    int r = g * 256 + q * 64 + h;
    wih_l[tid] = Wih[r];
    bb_l[tid] = bih[r] + bhh[r];
  }
  if (tid < 64) wenc_sl[tid] = gwenc[b * NT + q * 64 + tid];

  // vd / Svd with m = l*8+j mapping
  float vr[8];
  #pragma unroll
  for (int j = 0; j < 8; ++j) vr[j] = vd[l * 8 + j];
  float sv = 0.0f;
  #pragma unroll
  for (int j = 0; j < 8; ++j) sv += vr[j];
  #pragma unroll
  for (int off = 32; off > 0; off >>= 1) sv += __shfl_xor(sv, off, 64);
  const float Svd = sv;
  const float wtw512 = wtw[NM];
  const float wtb0 = wtb[0];

  // ---- persistent register tiles ----
  // y1 slice: wave w owns te_loc = w*4+i; lane l owns m = l*8..l*8+7
  short8v y1R[4];
  #pragma unroll
  for (int i = 0; i < 4; ++i)
    y1R[i] = *(const short8v*)(y1bf + ((size_t)(b * NT + q * 64 + w * 4 + i) << 9) + l * 8);
  // enc slice for c_t: waves 8..15, te_loc = (w-8)*8+i
  const int w8 = w - 8;
  short8v encR[8];
  if (w >= 8) {
    #pragma unroll
    for (int i = 0; i < 8; ++i)
      encR[i] = *(const short8v*)(encbf + ((size_t)(b * NT + q * 64 + w8 * 8 + i) << 9) + l * 8);
  }
  float ctacc[8] = {0,0,0,0,0,0,0,0};

  // ---- stage Wd k-slice into LDS, granule-swizzled ----
  // row m (512 rows) x 64 dwords (128 k as bf16 pairs). pair p=k/2, granule
  // g=p>>2 in [0,16); phys granule = g ^ (m&15). k<64 -> col q*64+k (d part),
  // k>=64 -> col 256+q*64+(k-64) (s part).
  {
    int m = tid >> 1, kh = tid & 1;
    for (int j = 0; j < 32; ++j) {
      int p = kh * 32 + j;
      int k0 = 2 * p, k1 = 2 * p + 1;
      int c0 = (k0 < 64) ? q * 64 + k0 : 256 + q * 64 + (k0 - 64);
      int c1 = (k1 < 64) ? q * 64 + k1 : 256 + q * 64 + (k1 - 64);
      u32 lo = wdbf[m * 512 + c0];
      u32 hi = wdbf[m * 512 + c1];
      int g = p >> 2, pg = g ^ (m & 15);
      wdsl[m * 64 + pg * 4 + (p & 3)] = lo | (hi << 16);
    }
  }

  float s_reg = 0.0f;    // tid<64: own cell state c[h]
  __syncthreads();

  float* gxb = gx + b * 2304;
  float* stb = st + b * 16;
  u32* fS = flags + b * 32;
  u32* fP = flags + b * 32 + 8;

  #pragma unroll 1
  for (int t = 0; t < NT; ++t) {
    // ---- A: wait for prev-step partials; assemble x1, d ----
    pollflags(fP, (u32)t);
    if (tid < 512) {
      const float* p = gxb + tid;
      float a0, a1, a2, a3;
      unc_ld1x4(p, p + 576, p + 1152, p + 1728, a0, a1, a2, a3);
      x1_l[tid] = K2 * (wdb_l[tid] + ((a0 + a1) + (a2 + a3)));
    } else if (tid < 768) {
      int h = tid - 512;
      d_l[h] = unc_ld1(gxb + (h >> 6) * 576 + 512 + (h & 63));
    }
    __syncthreads();  // (1)

    // ---- B: l_it from registers (4 te per wave) ----
    {
      const f32x4 x0 = *(const f32x4*)(x1_l + l * 8);
      const f32x4 x1v = *(const f32x4*)(x1_l + l * 8 + 4);
      float xr[8] = {x0[0], x0[1], x0[2], x0[3], x1v[0], x1v[1], x1v[2], x1v[3]};
      #pragma unroll
      for (int i = 0; i < 4; ++i) {
        float a = 0.0f;
        #pragma unroll
        for (int j = 0; j < 8; ++j) {
          float e = __builtin_amdgcn_exp2f(xr[j] + bf2f((u16)y1R[i][j]));
          a = fmaf(vr[j], __builtin_amdgcn_rcpf(1.0f + e), a);
        }
        #pragma unroll
        for (int off = 32; off > 0; off >>= 1) a += __shfl_xor(a, off, 64);
        if (l == 0) l_sl[w * 4 + i] = Svd - 2.0f * a;
      }
    }
    __syncthreads();  // (2)

    // ---- C: wave0 stats publish; waves1-15 Whh GEMV (hides stats RT) ----
    if (w == 0) {
      float v = l_sl[l];
      float mq = v;
      #pragma unroll
      for (int off = 32; off > 0; off >>= 1) mq = fmaxf(mq, __shfl_xor(mq, off, 64));
      float e = __builtin_amdgcn_exp2f((v - mq) * LOG2E);
      e_sl[l] = e;
      float sq = e, nq = e * wenc_sl[l];
      #pragma unroll
      for (int off = 32; off > 0; off >>= 1) {
        sq += __shfl_xor(sq, off, 64);
        nq += __shfl_xor(nq, off, 64);
      }
      if (l == 0) {
        f32x4 quad = {mq, sq, nq, 0.0f};
        unc_st4(stb + q * 4, quad);
        drain_vmem();
        unc_st1u(fS + q, (u32)(t + 1));
      }
    } else {
      #pragma unroll 1
      for (int pass = 0; pass < 2; ++pass) {
        int slot = (pass == 0) ? (tid - 64) : (tid - 64 + 960);
        if (pass == 1 && tid >= 128) break;
        int rl = slot >> 2, kq = slot & 3;
        const u16* wr = whhbf + (size_t)((rl >> 6) * 256 + q * 64 + (rl & 63)) * 256 + kq * 64;
        float a = 0.0f;
        #pragma unroll
        for (int c8 = 0; c8 < 8; ++c8) {
          short8v wv = *(const short8v*)(wr + c8 * 8);
          #pragma unroll
          for (int jj = 0; jj < 8; ++jj)
            a = fmaf(bf2f((u16)wv[jj]), d_l[kq * 64 + c8 * 8 + jj], a);
        }
        a += __shfl_xor(a, 1, 64);
        a += __shfl_xor(a, 2, 64);
        if (kq == 0) whh_d_l[rl] = a;
      }
    }

    // ---- D: poll stats, merge softmax, yt (all threads, one RT) ----
    pollflags(fS, (u32)(t + 1));
    f32x4 s0, s1, s2, s3;
    unc_ld16f(stb, s0, s1, s2, s3);
    float mx = fmaxf(fmaxf(s0[0], s1[0]), fmaxf(s2[0], s3[0]));
    float w0 = __builtin_amdgcn_exp2f((s0[0] - mx) * LOG2E);
    float w1 = __builtin_amdgcn_exp2f((s1[0] - mx) * LOG2E);
    float w2 = __builtin_amdgcn_exp2f((s2[0] - mx) * LOG2E);
    float w3 = __builtin_amdgcn_exp2f((s3[0] - mx) * LOG2E);
    float den = fmaf(s0[1], w0, fmaf(s1[1], w1, fmaf(s2[1], w2, s3[1] * w3)));
    float rden = __builtin_amdgcn_rcpf(den);
    float nsum = fmaf(s0[2], w0, fmaf(s1[2], w1, fmaf(s2[2], w2, s3[2] * w3)));
    float yt = nsum * rden + wtw512 * yin[b * NT + t] + wtb0;
    float wq = (q == 0) ? w0 : (q == 1) ? w1 : (q == 2) ? w2 : w3;
    float sc_q = wq * rden;
    __syncthreads();  // (3) whh_d_l + e_sl ready

    // ---- E: wave0 cell update ; waves 8-15 c_t accumulation (overlap) ----
    if (tid < 64) {
      int h = tid;
      float gi = sigmoid_fast(whh_d_l[h]       + yt * wih_l[h]       + bb_l[h]);
      float gf = sigmoid_fast(whh_d_l[64 + h]  + yt * wih_l[64 + h]  + bb_l[64 + h]);
      float gg = tanh_fast   (whh_d_l[128 + h] + yt * wih_l[128 + h] + bb_l[128 + h]);
      float go = sigmoid_fast(whh_d_l[192 + h] + yt * wih_l[192 + h] + bb_l[192 + h]);
      float sn = gf * s_reg + gi * gg;
      s_reg = sn;
      float dn = go * tanh_fast(sn);
      ds_f[h] = dn;
      ds_f[64 + h] = sn;
      unc_st1(gxb + q * 576 + 512 + h, dn);
    } else if (w >= 8) {
      float tmp[8] = {0,0,0,0,0,0,0,0};
      #pragma unroll
      for (int i = 0; i < 8; ++i) {
        float e = e_sl[w8 * 8 + i];
        #pragma unroll
        for (int j = 0; j < 8; ++j)
          tmp[j] = fmaf(bf2f((u16)encR[i][j]), e, tmp[j]);
      }
      #pragma unroll
      for (int j = 0; j < 8; ++j) ctacc[j] = fmaf(sc_q, tmp[j], ctacc[j]);
    }
    __syncthreads();  // (4) ds_f ready

    // ---- F: waves0-7: x1-partial GEMV (1 lane = 1 m, full 128-k dot) ----
    if (w < 8) {
      int m = w * 64 + l;
      const u32* row = wdsl + m * 64;
      const int sw = (m & 15) << 2;
      float a = 0.0f;
      #pragma unroll
      for (int g = 0; g < 16; ++g) {
        u32x4 wv = *(const u32x4*)(row + (((g << 2) ^ sw)));
        f32x4 d0 = *(const f32x4*)(ds_f + g * 8);
        f32x4 d1 = *(const f32x4*)(ds_f + g * 8 + 4);
        #pragma unroll
        for (int n = 0; n < 4; ++n) {
          u32 v = wv[n];
          float wlo = bits2f(v << 16);
          float whi = bits2f(v & 0xffff0000u);
          float dlo = (n < 2) ? d0[2 * n] : d1[2 * n - 4];
          float dhi = (n < 2) ? d0[2 * n + 1] : d1[2 * n - 3];
          a = fmaf(wlo, dlo, a);
          a = fmaf(whi, dhi, a);
        }
      }
      unc_st1(gxb + q * 576 + m, a);
    }
    drain_vmem();
    __syncthreads();  // (5) all stores drained
    if (tid == 0) unc_st1u(fP + q, (u32)(t + 1));
  }

  // ---- final: c_t accumulators -> out ----
  if (w >= 8) {
    #pragma unroll
    for (int j = 0; j < 8; ++j)
      __hip_atomic_fetch_add(&out[b * NM + l * 8 + j], ctacc[j],
                             __ATOMIC_RELAXED, __HIP_MEMORY_SCOPE_SYSTEM);
  }
}

extern "C" void kernel_launch(void* const* d_in, const int* in_sizes, int n_in,
                              void* d_out, int out_size, void* d_ws, size_t ws_size,
                              hipStream_t stream) {
  const float* enc  = (const float*)d_in[0];
  const float* yin  = (const float*)d_in[1];
  const float* Wd_w = (const float*)d_in[2];
  const float* Wd_b = (const float*)d_in[3];
  const float* Ud_w = (const float*)d_in[4];
  const float* vd_w = (const float*)d_in[5];
  const float* wt_w = (const float*)d_in[6];
  const float* wt_b = (const float*)d_in[7];
  const float* Wih  = (const float*)d_in[8];
  const float* Whh  = (const float*)d_in[9];
  const float* bih  = (const float*)d_in[10];
  const float* bhh  = (const float*)d_in[11];

  char* ws = (char*)d_ws;
  u16*   y1bf  = (u16*)(ws);                      // 16,777,216
  u16*   encbf = (u16*)(ws + 16777216);           // 16,777,216
  u16*   udbf  = (u16*)(ws + 33554432);           // 524,288
  u16*   wdbf  = (u16*)(ws + 34078720);           // 524,288
  u16*   whhbf = (u16*)(ws + 34603008);           // 524,288
  float* gwenc = (float*)(ws + 35127296);         // 65,536
  float* gx    = (float*)(ws + 35192832);         // 589,824
  float* st    = (float*)(ws + 35782656);         // 4,096
  u32*   flags = (u32*)(ws + 35786752);           // 8,192

  // zero mutable state: gx, st, flags; and d_out (atomic accumulation target)
  hipMemsetAsync(ws + 35192832, 0, 602112, stream);
  hipMemsetAsync(d_out, 0, (size_t)out_size * sizeof(float), stream);

  convert_f32_bf16<<<8388608 / 256, 256, 0, stream>>>(enc, encbf, 8388608);
  convert_f32_bf16<<<262144 / 256, 256, 0, stream>>>(Ud_w, udbf, 262144);
  convert_f32_bf16<<<262144 / 256, 256, 0, stream>>>(Wd_w, wdbf, 262144);
  convert_f32_bf16<<<262144 / 256, 256, 0, stream>>>(Whh, whhbf, 262144);
  gemm_y1<<<dim3(256, 8), 256, 0, stream>>>(encbf, udbf, y1bf);
  wenc_kernel<<<64, 256, 0, stream>>>(encbf, wt_w, gwenc);

  hipFuncSetAttribute((const void*)attn_scan,
                      hipFuncAttributeMaxDynamicSharedMemorySize, 131072);
  attn_scan<<<256, 1024, 131072, stream>>>(y1bf, encbf, whhbf, wdbf, Wd_b, vd_w,
                                           wt_w, wt_b, Wih, bih, bhh, yin, gwenc,
                                           gx, st, flags, (float*)d_out);
}

// Round 6
// 4234.605 us; speedup vs baseline: 1.4583x; 1.4583x over previous
//
#include <hip/hip_runtime.h>

typedef unsigned short u16;
typedef unsigned int u32;
typedef __attribute__((ext_vector_type(8))) short short8v;
typedef __attribute__((ext_vector_type(4))) float f32x4;
typedef __attribute__((ext_vector_type(4))) unsigned int u32x4;

#define NB 64
#define NT 256
#define NM 512
#define NH 256

#define K2 2.8853900817779268f   // 2*log2(e)
#define LOG2E 1.4426950408889634f

__device__ __forceinline__ float bf2f(u16 u) {
  union { unsigned i; float f; } c; c.i = ((unsigned)u) << 16; return c.f;
}
__device__ __forceinline__ u16 f2bf(float f) {
  union { float fv; unsigned i; } c; c.fv = f;
  unsigned i = c.i;
  return (u16)((i + 0x7fffu + ((i >> 16) & 1u)) >> 16);
}
__device__ __forceinline__ float bits2f(u32 u) {
  union { unsigned i; float f; } c; c.i = u; return c.f;
}
__device__ __forceinline__ float tanh_fast(float x) {
  return 1.0f - 2.0f * __builtin_amdgcn_rcpf(1.0f + __builtin_amdgcn_exp2f(K2 * x));
}
__device__ __forceinline__ float sigmoid_fast(float x) {
  return __builtin_amdgcn_rcpf(1.0f + __builtin_amdgcn_exp2f(-LOG2E * x));
}

// ---- uncached (sc0 sc1: bypass L1/L2, coherence point = IF) helpers ----
__device__ __forceinline__ float unc_ld1(const float* p) {
  float r;
  asm volatile("global_load_dword %0, %1, off sc0 sc1\n\ts_waitcnt vmcnt(0)"
               : "=&v"(r) : "v"(p) : "memory");
  return r;
}
__device__ __forceinline__ void unc_ld1x4(const float* p0, const float* p1,
                                          const float* p2, const float* p3,
                                          float& a0, float& a1, float& a2, float& a3) {
  asm volatile(
      "global_load_dword %0, %4, off sc0 sc1\n\t"
      "global_load_dword %1, %5, off sc0 sc1\n\t"
      "global_load_dword %2, %6, off sc0 sc1\n\t"
      "global_load_dword %3, %7, off sc0 sc1\n\t"
      "s_waitcnt vmcnt(0)"
      : "=&v"(a0), "=&v"(a1), "=&v"(a2), "=&v"(a3)
      : "v"(p0), "v"(p1), "v"(p2), "v"(p3)
      : "memory");
}
// 4 consecutive dwordx4 from one base, ONE waitcnt (offset: BEFORE sc flags)
__device__ __forceinline__ void unc_ld16f(const float* p, f32x4& a, f32x4& b,
                                          f32x4& c, f32x4& d) {
  asm volatile(
      "global_load_dwordx4 %0, %4, off sc0 sc1\n\t"
      "global_load_dwordx4 %1, %4, off offset:16 sc0 sc1\n\t"
      "global_load_dwordx4 %2, %4, off offset:32 sc0 sc1\n\t"
      "global_load_dwordx4 %3, %4, off offset:48 sc0 sc1\n\t"
      "s_waitcnt vmcnt(0)"
      : "=&v"(a), "=&v"(b), "=&v"(c), "=&v"(d)
      : "v"(p) : "memory");
}
__device__ __forceinline__ void unc_st1(float* p, float v) {
  asm volatile("global_store_dword %0, %1, off sc0 sc1" :: "v"(p), "v"(v) : "memory");
}
__device__ __forceinline__ void unc_st1u(u32* p, u32 v) {
  asm volatile("global_store_dword %0, %1, off sc0 sc1" :: "v"(p), "v"(v) : "memory");
}
__device__ __forceinline__ void unc_st4(float* p, f32x4 v) {
  asm volatile("global_store_dwordx4 %0, %1, off sc0 sc1" :: "v"(p), "v"(v) : "memory");
}
__device__ __forceinline__ void drain_vmem() {
  asm volatile("s_waitcnt vmcnt(0)" ::: "memory");
}
__device__ __forceinline__ void pollflags(const u32* p, u32 tg) {
  for (;;) {
    u32x4 f;
    asm volatile("global_load_dwordx4 %0, %1, off sc0 sc1\n\ts_waitcnt vmcnt(0)"
                 : "=&v"(f) : "v"(p) : "memory");
    if (f[0] >= tg && f[1] >= tg && f[2] >= tg && f[3] >= tg) break;
    __builtin_amdgcn_s_sleep(1);
  }
}

__global__ void convert_f32_bf16(const float* __restrict__ in, u16* __restrict__ out, int n) {
  int i = blockIdx.x * blockDim.x + threadIdx.x;
  if (i < n) out[i] = f2bf(in[i]);
}

// y1' = K2 * enc @ Ud^T  (bf16 out, prescaled for exp2-based tanh)
__global__ __launch_bounds__(256) void gemm_y1(const u16* __restrict__ A,
                                               const u16* __restrict__ Bm,
                                               u16* __restrict__ C) {
  const int w = threadIdx.x >> 6;
  const int l = threadIdx.x & 63;
  const int kg = l >> 4;
  const int r16 = l & 15;
  const int rowbase = blockIdx.x * 64 + w * 16;
  const int colbase = blockIdx.y * 64;
  const u16* ap = A + (size_t)(rowbase + r16) * 512 + kg * 8;
  f32x4 acc0 = {0,0,0,0}, acc1 = {0,0,0,0}, acc2 = {0,0,0,0}, acc3 = {0,0,0,0};
  for (int k = 0; k < 512; k += 32) {
    short8v af = *(const short8v*)(ap + k);
    const u16* bp = Bm + (size_t)(colbase + r16) * 512 + kg * 8 + k;
    short8v b0 = *(const short8v*)(bp);
    short8v b1 = *(const short8v*)(bp + 16 * 512);
    short8v b2 = *(const short8v*)(bp + 32 * 512);
    short8v b3 = *(const short8v*)(bp + 48 * 512);
    acc0 = __builtin_amdgcn_mfma_f32_16x16x32_bf16(af, b0, acc0, 0, 0, 0);
    acc1 = __builtin_amdgcn_mfma_f32_16x16x32_bf16(af, b1, acc1, 0, 0, 0);
    acc2 = __builtin_amdgcn_mfma_f32_16x16x32_bf16(af, b2, acc2, 0, 0, 0);
    acc3 = __builtin_amdgcn_mfma_f32_16x16x32_bf16(af, b3, acc3, 0, 0, 0);
  }
  #pragma unroll
  for (int j = 0; j < 4; ++j) {
    int r = rowbase + (l >> 4) * 4 + j;
    C[(size_t)r * 512 + colbase +  0 + r16] = f2bf(K2 * acc0[j]);
    C[(size_t)r * 512 + colbase + 16 + r16] = f2bf(K2 * acc1[j]);
    C[(size_t)r * 512 + colbase + 32 + r16] = f2bf(K2 * acc2[j]);
    C[(size_t)r * 512 + colbase + 48 + r16] = f2bf(K2 * acc3[j]);
  }
}

// w_enc[b,te] = sum_m enc[b,te,m] * wtw[m]
__global__ __launch_bounds__(256) void wenc_kernel(const u16* __restrict__ encbf,
                                                   const float* __restrict__ wtw,
                                                   float* __restrict__ gwenc) {
  int b = blockIdx.x, te = threadIdx.x;
  const u16* ep = encbf + ((size_t)(b * NT + te)) * NM;
  float a = 0.0f;
  for (int c8 = 0; c8 < 64; ++c8) {
    short8v v = *(const short8v*)(ep + c8 * 8);
    #pragma unroll
    for (int jj = 0; jj < 8; ++jj) a = fmaf(bf2f((u16)v[jj]), wtw[c8 * 8 + jj], a);
  }
  gwenc[b * NT + te] = a;
}

// out[b,m] = sum_te betaAcc[b,te] * enc[b,te,m]
__global__ __launch_bounds__(512) void bsum_kernel(const u16* __restrict__ encbf,
                                                   const float* __restrict__ gbeta,
                                                   float* __restrict__ out) {
  __shared__ float bl[NT];
  int b = blockIdx.x, m = threadIdx.x;
  if (m < 256) bl[m] = gbeta[b * NT + m];
  __syncthreads();
  const u16* ep = encbf + (size_t)b * NT * NM + m;
  float a = 0.0f;
  #pragma unroll 8
  for (int te = 0; te < NT; ++te)
    a = fmaf(bf2f(ep[(size_t)te * NM]), bl[te], a);
  out[b * NM + m] = a;
}

__attribute__((amdgpu_waves_per_eu(4, 4)))
__global__ void __launch_bounds__(1024) attn_scan(
    const u16* __restrict__ y1bf,    // [B,T,M] prescaled by K2
    const u16* __restrict__ whhbf,   // [1024,256]
    const u16* __restrict__ wdbf,    // [M,512]
    const float* __restrict__ Wd_b,  // [512]
    const float* __restrict__ vd,    // [512]
    const float* __restrict__ wtw,   // [513]
    const float* __restrict__ wtb,   // [1]
    const float* __restrict__ Wih,   // [1024]
    const float* __restrict__ bih,   // [1024]
    const float* __restrict__ bhh,   // [1024]
    const float* __restrict__ yin,   // [B,T]
    const float* __restrict__ gwenc, // [B,256]
    float* __restrict__ gx,          // [B][4][576]: 512 x1-partial + 64 dnew
    float* __restrict__ st,          // [B][4][4]: m_q, s_q, n_q, pad
    u32* __restrict__ flags,         // [B][32]: [0..3]=fS, [8..11]=fP
    float* __restrict__ gbeta)       // [B,256] sum_t beta
{
  extern __shared__ char ldsraw[];
  u32* wdsl = (u32*)ldsraw;          // [512 m][64 dw] swizzled bf16 pairs, 128 KiB

  __shared__ float x1_l2[NM];        // [j][lane]: idx j*64+lane holds x1[lane*8+j]
  __shared__ float d_l[NH];
  __shared__ float ds_f[128];        // dn(64) ; sn(64)
  __shared__ float l_sl[64];
  __shared__ float e_sl[64];
  __shared__ float whh_d_l[256];
  __shared__ float wih_l[256];
  __shared__ float bb_l[256];
  __shared__ float wenc_sl[64];
  __shared__ float yin_l[NT];
  __shared__ float merged[8];        // yt, w0..w3, rden

  const int tid = threadIdx.x;
  const int bid = blockIdx.x;
  const int xcd = bid & 7, ii = bid >> 3;
  const int b = (xcd << 3) | (ii >> 2);
  const int q = ii & 3;
  const int w = tid >> 6, l = tid & 63;

  // ---- one-time init ----
  if (tid < 256) {
    int g = tid >> 6, h = tid & 63;
    int r = g * 256 + q * 64 + h;
    wih_l[tid] = Wih[r];
    bb_l[tid] = bih[r] + bhh[r];
    yin_l[tid] = yin[b * NT + tid];
  }
  if (tid < 64) wenc_sl[tid] = gwenc[b * NT + q * 64 + tid];

  float vr[8];
  #pragma unroll
  for (int j = 0; j < 8; ++j) vr[j] = vd[l * 8 + j];
  float sv = 0.0f;
  #pragma unroll
  for (int j = 0; j < 8; ++j) sv += vr[j];
  #pragma unroll
  for (int off = 32; off > 0; off >>= 1) sv += __shfl_xor(sv, off, 64);
  const float Svd = sv;
  const float wtw512 = wtw[NM];
  const float wtb0 = wtb[0];
  const float wdb_r = (tid < 512) ? Wd_b[tid] : 0.0f;

  // ---- persistent y1 register tile: wave w owns te = q*64 + w*4 + i ----
  u32x4 y1R0, y1R1, y1R2, y1R3;
  {
    const u16* base = y1bf + ((size_t)(b * NT + q * 64 + w * 4) << 9) + l * 8;
    y1R0 = *(const u32x4*)(base);
    y1R1 = *(const u32x4*)(base + 512);
    y1R2 = *(const u32x4*)(base + 1024);
    y1R3 = *(const u32x4*)(base + 1536);
  }
  // opaque-launder: prevents remat of the loads inside the loop
  asm volatile("" : "+v"(y1R0), "+v"(y1R1), "+v"(y1R2), "+v"(y1R3));

  // ---- stage Wd k-slice into LDS, granule-swizzled ----
  // pair p (=k/2) 0..63 per row m; granule g=p>>2; phys = g ^ (m&15) ^ ((m>>4)&3)
  {
    int m = tid >> 1, kh = tid & 1;
    for (int j = 0; j < 32; ++j) {
      int p = kh * 32 + j;
      int k0 = 2 * p, k1 = 2 * p + 1;
      int c0 = (k0 < 64) ? q * 64 + k0 : 256 + q * 64 + (k0 - 64);
      int c1 = (k1 < 64) ? q * 64 + k1 : 256 + q * 64 + (k1 - 64);
      u32 lo = wdbf[m * 512 + c0];
      u32 hi = wdbf[m * 512 + c1];
      int pg = (p >> 2) ^ (m & 15) ^ ((m >> 4) & 3);
      wdsl[m * 64 + pg * 4 + (p & 3)] = lo | (hi << 16);
    }
  }

  float s_reg = 0.0f;   // wave0: own cell state c[h]
  float bacc = 0.0f;    // wave1: sum_t beta[t][q*64+l]
  __syncthreads();

  float* gxb = gx + b * 2304;
  float* stb = st + b * 16;
  u32* fS = flags + b * 32;
  u32* fP = flags + b * 32 + 8;

  #pragma unroll 1
  for (int t = 0; t < NT; ++t) {
    // ---- A: wave15 polls prev-step partials flag; others wait at barrier ----
    if (w == 15) pollflags(fP, (u32)t);
    __syncthreads();  // A

    if (tid < 512) {
      const float* p = gxb + tid;
      float a0, a1, a2, a3;
      unc_ld1x4(p, p + 576, p + 1152, p + 1728, a0, a1, a2, a3);
      x1_l2[(tid & 7) * 64 + (tid >> 3)] = K2 * (wdb_r + ((a0 + a1) + (a2 + a3)));
    } else if (tid < 768) {
      int h = tid - 512;
      d_l[h] = unc_ld1(gxb + (h >> 6) * 576 + 512 + (h & 63));
    }
    __syncthreads();  // B

    // ---- l_it from registers (4 te per wave) ----
    {
      float xr[8];
      #pragma unroll
      for (int j = 0; j < 8; ++j) xr[j] = x1_l2[j * 64 + l];
      auto lit = [&](u32x4 V, int idx) {
        float a = 0.0f;
        #pragma unroll
        for (int n = 0; n < 4; ++n) {
          u32 v = V[n];
          float e0 = __builtin_amdgcn_exp2f(xr[2 * n] + bits2f(v << 16));
          a = fmaf(vr[2 * n], __builtin_amdgcn_rcpf(1.0f + e0), a);
          float e1 = __builtin_amdgcn_exp2f(xr[2 * n + 1] + bits2f(v & 0xffff0000u));
          a = fmaf(vr[2 * n + 1], __builtin_amdgcn_rcpf(1.0f + e1), a);
        }
        #pragma unroll
        for (int off = 32; off > 0; off >>= 1) a += __shfl_xor(a, off, 64);
        if (l == 0) l_sl[w * 4 + idx] = Svd - 2.0f * a;
      };
      lit(y1R0, 0); lit(y1R1, 1); lit(y1R2, 2); lit(y1R3, 3);
    }
    __syncthreads();  // C

    // ---- wave0: stats publish | waves1-8: Whh GEMV | wave15: stats merge ----
    if (w == 0) {
      float v = l_sl[l];
      float mq = v;
      #pragma unroll
      for (int off = 32; off > 0; off >>= 1) mq = fmaxf(mq, __shfl_xor(mq, off, 64));
      float e = __builtin_amdgcn_exp2f((v - mq) * LOG2E);
      e_sl[l] = e;
      float sq = e, nq = e * wenc_sl[l];
      #pragma unroll
      for (int off = 32; off > 0; off >>= 1) {
        sq += __shfl_xor(sq, off, 64);
        nq += __shfl_xor(nq, off, 64);
      }
      if (l == 0) {
        f32x4 quad = {mq, sq, nq, 0.0f};
        unc_st4(stb + q * 4, quad);
        drain_vmem();
        unc_st1u(fS + q, (u32)(t + 1));
      }
    } else if (w <= 8) {
      #pragma unroll 1
      for (int pass = 0; pass < 2; ++pass) {
        int slot = (w - 1) * 64 + l + pass * 512;
        int rl = slot >> 2, kq = slot & 3;
        const u16* wr = whhbf + (size_t)((rl >> 6) * 256 + q * 64 + (rl & 63)) * 256 + kq * 64;
        float a = 0.0f;
        #pragma unroll
        for (int c8 = 0; c8 < 8; ++c8) {
          short8v wv = *(const short8v*)(wr + c8 * 8);
          #pragma unroll
          for (int jj = 0; jj < 8; ++jj)
            a = fmaf(bf2f((u16)wv[jj]), d_l[kq * 64 + c8 * 8 + jj], a);
        }
        a += __shfl_xor(a, 1, 64);
        a += __shfl_xor(a, 2, 64);
        if (kq == 0) whh_d_l[rl] = a;
      }
    } else if (w == 15) {
      pollflags(fS, (u32)(t + 1));
      f32x4 s0, s1, s2, s3;
      unc_ld16f(stb, s0, s1, s2, s3);
      float mx = fmaxf(fmaxf(s0[0], s1[0]), fmaxf(s2[0], s3[0]));
      float w0 = __builtin_amdgcn_exp2f((s0[0] - mx) * LOG2E);
      float w1 = __builtin_amdgcn_exp2f((s1[0] - mx) * LOG2E);
      float w2 = __builtin_amdgcn_exp2f((s2[0] - mx) * LOG2E);
      float w3 = __builtin_amdgcn_exp2f((s3[0] - mx) * LOG2E);
      float den = fmaf(s0[1], w0, fmaf(s1[1], w1, fmaf(s2[1], w2, s3[1] * w3)));
      float rden = __builtin_amdgcn_rcpf(den);
      float nsum = fmaf(s0[2], w0, fmaf(s1[2], w1, fmaf(s2[2], w2, s3[2] * w3)));
      float yt = nsum * rden + wtw512 * yin_l[t] + wtb0;
      if (l == 0) {
        merged[0] = yt; merged[1] = w0; merged[2] = w1;
        merged[3] = w2; merged[4] = w3; merged[5] = rden;
      }
    }
    __syncthreads();  // D

    // ---- wave0: cell update | wave1: beta accumulation ----
    if (tid < 64) {
      float yt = merged[0];
      int h = tid;
      float gi = sigmoid_fast(whh_d_l[h]       + yt * wih_l[h]       + bb_l[h]);
      float gf = sigmoid_fast(whh_d_l[64 + h]  + yt * wih_l[64 + h]  + bb_l[64 + h]);
      float gg = tanh_fast   (whh_d_l[128 + h] + yt * wih_l[128 + h] + bb_l[128 + h]);
      float go = sigmoid_fast(whh_d_l[192 + h] + yt * wih_l[192 + h] + bb_l[192 + h]);
      float sn = gf * s_reg + gi * gg;
      s_reg = sn;
      float dn = go * tanh_fast(sn);
      ds_f[h] = dn;
      ds_f[64 + h] = sn;
      unc_st1(gxb + q * 576 + 512 + h, dn);
    } else if (w == 1) {
      float sc_q = merged[1 + q] * merged[5];
      bacc = fmaf(e_sl[l], sc_q, bacc);
    }
    __syncthreads();  // E

    // ---- waves0-7: x1-partial GEMV (1 lane = 1 m, full 128-k dot) ----
    if (w < 8) {
      int m = w * 64 + l;
      const u32* row = wdsl + m * 64;
      const int sx = ((m & 15) ^ ((m >> 4) & 3)) << 2;
      float a = 0.0f;
      #pragma unroll
      for (int g = 0; g < 16; ++g) {
        u32x4 wv = *(const u32x4*)(row + ((g << 2) ^ sx));
        f32x4 d0 = *(const f32x4*)(ds_f + g * 8);
        f32x4 d1 = *(const f32x4*)(ds_f + g * 8 + 4);
        #pragma unroll
        for (int n = 0; n < 4; ++n) {
          u32 v = wv[n];
          float wlo = bits2f(v << 16);
          float whi = bits2f(v & 0xffff0000u);
          float dlo = (n < 2) ? d0[2 * n] : d1[2 * n - 4];
          float dhi = (n < 2) ? d0[2 * n + 1] : d1[2 * n - 3];
          a = fmaf(wlo, dlo, a);
          a = fmaf(whi, dhi, a);
        }
      }
      unc_st1(gxb + q * 576 + m, a);
    }
    drain_vmem();
    __syncthreads();  // F
    if (tid == 0) unc_st1u(fP + q, (u32)(t + 1));
  }

  if (w == 1) gbeta[b * NT + q * 64 + l] = bacc;
}

extern "C" void kernel_launch(void* const* d_in, const int* in_sizes, int n_in,
                              void* d_out, int out_size, void* d_ws, size_t ws_size,
                              hipStream_t stream) {
  const float* enc  = (const float*)d_in[0];
  const float* yin  = (const float*)d_in[1];
  const float* Wd_w = (const float*)d_in[2];
  const float* Wd_b = (const float*)d_in[3];
  const float* Ud_w = (const float*)d_in[4];
  const float* vd_w = (const float*)d_in[5];
  const float* wt_w = (const float*)d_in[6];
  const float* wt_b = (const float*)d_in[7];
  const float* Wih  = (const float*)d_in[8];
  const float* Whh  = (const float*)d_in[9];
  const float* bih  = (const float*)d_in[10];
  const float* bhh  = (const float*)d_in[11];

  char* ws = (char*)d_ws;
  u16*   y1bf  = (u16*)(ws);                      // 16,777,216
  u16*   encbf = (u16*)(ws + 16777216);           // 16,777,216
  u16*   udbf  = (u16*)(ws + 33554432);           // 524,288
  u16*   wdbf  = (u16*)(ws + 34078720);           // 524,288
  u16*   whhbf = (u16*)(ws + 34603008);           // 524,288
  float* gwenc = (float*)(ws + 35127296);         // 65,536
  float* gx    = (float*)(ws + 35192832);         // 589,824
  float* st    = (float*)(ws + 35782656);         // 4,096
  u32*   flags = (u32*)(ws + 35786752);           // 8,192
  float* gbeta = (float*)(ws + 35794944);         // 65,536

  // zero mutable state: gx, st, flags
  hipMemsetAsync(ws + 35192832, 0, 602112, stream);

  convert_f32_bf16<<<8388608 / 256, 256, 0, stream>>>(enc, encbf, 8388608);
  convert_f32_bf16<<<262144 / 256, 256, 0, stream>>>(Ud_w, udbf, 262144);
  convert_f32_bf16<<<262144 / 256, 256, 0, stream>>>(Wd_w, wdbf, 262144);
  convert_f32_bf16<<<262144 / 256, 256, 0, stream>>>(Whh, whhbf, 262144);
  gemm_y1<<<dim3(256, 8), 256, 0, stream>>>(encbf, udbf, y1bf);
  wenc_kernel<<<64, 256, 0, stream>>>(encbf, wt_w, gwenc);

  hipFuncSetAttribute((const void*)attn_scan,
                      hipFuncAttributeMaxDynamicSharedMemorySize, 131072);
  attn_scan<<<256, 1024, 131072, stream>>>(y1bf, whhbf, wdbf, Wd_b, vd_w,
                                           wt_w, wt_b, Wih, bih, bhh, yin, gwenc,
                                           gx, st, flags, gbeta);
  bsum_kernel<<<64, 512, 0, stream>>>(encbf, gbeta, (float*)d_out);
}